// Round 2
// baseline (801.387 us; speedup 1.0000x reference)
//
#include <hip/hip_runtime.h>

#define NN 512
#define ND 1024
#define NDW 524288   // N*D
#define NBATCH 64

typedef __attribute__((ext_vector_type(8))) __bf16 bf16x8;
typedef __attribute__((ext_vector_type(4))) float f32x4;
typedef unsigned short u16;
typedef unsigned int u32;

__device__ __forceinline__ u16 f2bf(float x) {
    u32 u = __float_as_uint(x);
    u = (u + 0x7fffu + ((u >> 16) & 1u)) >> 16;   // RNE
    return (u16)u;
}

__global__ __launch_bounds__(256)
void nma_init_out(float* __restrict__ out, const float* __restrict__ fcb) {
    int t = threadIdx.x;
    if (t < NBATCH * 4) out[t] = fcb[t & 3];
}

// Qe = bf16(Q + emb[eid]), Ke = bf16(K + emb[eid]), row-major [B,N,D].
// Fused: emb row loaded once, used for both.
__global__ __launch_bounds__(256)
void prep_qk(const float* __restrict__ Q, const float* __restrict__ K,
             const int* __restrict__ eid, const float* __restrict__ emb,
             u16* __restrict__ Qe, u16* __restrict__ Ke) {
    size_t f = ((size_t)blockIdx.x * 256 + threadIdx.x) * 8;
    int n = (int)((f >> 10) & (NN - 1));
    int col = (int)(f & (ND - 1));
    const float* ep = emb + (size_t)eid[n] * ND + col;
    float4 e0 = *(const float4*)ep, e1 = *(const float4*)(ep + 4);
    {
        const float* qp = Q + f;
        float4 x0 = *(const float4*)qp, x1 = *(const float4*)(qp + 4);
        union { uint4 u; u16 s[8]; } o;
        o.s[0]=f2bf(x0.x+e0.x); o.s[1]=f2bf(x0.y+e0.y); o.s[2]=f2bf(x0.z+e0.z); o.s[3]=f2bf(x0.w+e0.w);
        o.s[4]=f2bf(x1.x+e1.x); o.s[5]=f2bf(x1.y+e1.y); o.s[6]=f2bf(x1.z+e1.z); o.s[7]=f2bf(x1.w+e1.w);
        *(uint4*)(Qe + f) = o.u;
    }
    {
        const float* kp = K + f;
        float4 x0 = *(const float4*)kp, x1 = *(const float4*)(kp + 4);
        union { uint4 u; u16 s[8]; } o;
        o.s[0]=f2bf(x0.x+e0.x); o.s[1]=f2bf(x0.y+e0.y); o.s[2]=f2bf(x0.z+e0.z); o.s[3]=f2bf(x0.w+e0.w);
        o.s[4]=f2bf(x1.x+e1.x); o.s[5]=f2bf(x1.y+e1.y); o.s[6]=f2bf(x1.z+e1.z); o.s[7]=f2bf(x1.w+e1.w);
        *(uint4*)(Ke + f) = o.u;
    }
}

// VT[b,d,n] = bf16(V[b,n,d] + emb[eid[n],d]) — 64x64 LDS tile transpose
__global__ __launch_bounds__(256)
void prep_vt(const float* __restrict__ V, const int* __restrict__ eid,
             const float* __restrict__ emb, u16* __restrict__ VT) {
    __shared__ u16 T[64 * 72];
    const int tid = threadIdx.x;
    const int b = blockIdx.z, d0 = blockIdx.y * 64, n0 = blockIdx.x * 64;
    {
        const int r = tid >> 2, cs = (tid & 3) * 16;
        const int n = n0 + r;
        const float* vp = V + ((size_t)b * NN + n) * ND + d0 + cs;
        const float* ep = emb + (size_t)eid[n] * ND + d0 + cs;
        #pragma unroll
        for (int j = 0; j < 4; ++j) {
            float4 v = *(const float4*)(vp + j * 4);
            float4 e = *(const float4*)(ep + j * 4);
            T[(cs + j*4 + 0) * 72 + r] = f2bf(v.x + e.x);
            T[(cs + j*4 + 1) * 72 + r] = f2bf(v.y + e.y);
            T[(cs + j*4 + 2) * 72 + r] = f2bf(v.z + e.z);
            T[(cs + j*4 + 3) * 72 + r] = f2bf(v.w + e.w);
        }
    }
    __syncthreads();
    {
        const int dr = tid >> 2, ms = (tid & 3) * 16;
        u16* dst = VT + ((size_t)b * ND + d0 + dr) * NN + n0 + ms;
        *(uint4*)dst       = *(const uint4*)&T[dr * 72 + ms];
        *(uint4*)(dst + 8) = *(const uint4*)&T[dr * 72 + ms + 8];
    }
}

// One block per (b, 32-row Q tile). Dead-path: neuromod term is per-row const,
// cancels in (ms-mean)/std -> only QK^T -> z-softmax -> PV -> FC survives.
// XCD swizzle: b = (bid&7) + 8*(bid>>7) so all 16 tiles of a batch share an XCD L2.
//
// DIRECT-REGISTER operands: wave w's MFMA B-rows (Ke/VT rows [w*128,w*128+128))
// are wave-private, and the fragment shape (16 rows x 16B) is exactly one
// global_load_dwordx4 — LDS staging bought nothing. No DMA, no ds_read for
// operands, no barriers in the K-loops; compiler pipelines reg-loads freely.
// LDS = Ps only (~36KB) -> 3 blocks/CU at launch_bounds(256,3).
// FC is fused into the epilogue from the f32 oacc (no O materialization).
__global__ __launch_bounds__(256, 3)
void nma_attn(const u16* __restrict__ Qe, const u16* __restrict__ Ke,
              const u16* __restrict__ VT, const float* __restrict__ fcw,
              float* __restrict__ out)
{
    __shared__ __align__(16) u16 Ps[32 * 520];    // probs bf16
    __shared__ float red[4][32][4];
    __shared__ float rowM[32], rowInv[32], rowRden[32];

    const int tid  = threadIdx.x;
    const int w    = tid >> 6;
    const int lane = tid & 63;
    const int q    = lane >> 4;
    const int l15  = lane & 15;
    const int bid  = blockIdx.x;
    const int jj   = bid >> 3;
    const int b    = (bid & 7) + ((jj >> 4) << 3);
    const int i0   = (jj & 15) * 32;
    const size_t bOff = (size_t)b * NN * ND;
    const int wrow = w * 128;     // wave-private B-operand row base

    f32x4 acc[2][8];
    #pragma unroll
    for (int it = 0; it < 2; ++it)
        #pragma unroll
        for (int mt = 0; mt < 8; ++mt)
            acc[it][mt] = (f32x4){0.f, 0.f, 0.f, 0.f};

    // ---- Phase 2: S = Qe * Ke^T (all operands direct from global) ----
    {
        const u16* aP0 = Qe + bOff + (size_t)(i0 + l15) * ND + q * 8;
        const u16* aP1 = aP0 + (size_t)16 * ND;
        const u16* bP  = Ke + bOff + (size_t)(wrow + l15) * ND + q * 8;
        for (int kc = 0; kc < 32; ++kc) {
            const int ko = kc * 32;
            bf16x8 a0 = *(const bf16x8*)(aP0 + ko);
            bf16x8 a1 = *(const bf16x8*)(aP1 + ko);
            #pragma unroll
            for (int mt = 0; mt < 8; ++mt) {
                bf16x8 bf = *(const bf16x8*)(bP + (size_t)(mt * 16) * ND + ko);
                acc[0][mt] = __builtin_amdgcn_mfma_f32_16x16x32_bf16(a0, bf, acc[0][mt], 0, 0, 0);
                acc[1][mt] = __builtin_amdgcn_mfma_f32_16x16x32_bf16(a1, bf, acc[1][mt], 0, 0, 0);
            }
        }
    }

    // ---- Phase 3: exact row stats (mean, ddof=1 std, max), softmax(z) ----
    const float SC = 0.03125f;
    #pragma unroll
    for (int it = 0; it < 2; ++it)
        #pragma unroll
        for (int mt = 0; mt < 8; ++mt) {
            acc[it][mt][0] *= SC; acc[it][mt][1] *= SC;
            acc[it][mt][2] *= SC; acc[it][mt][3] *= SC;
        }
    float ssum[2][4], ssq[2][4], smax[2][4];
    #pragma unroll
    for (int it = 0; it < 2; ++it)
        #pragma unroll
        for (int r = 0; r < 4; ++r) {
            float s = 0.f, s2 = 0.f, mx = -3.4e38f;
            #pragma unroll
            for (int mt = 0; mt < 8; ++mt) {
                float v = acc[it][mt][r];
                s += v; s2 += v * v; mx = fmaxf(mx, v);
            }
            #pragma unroll
            for (int d = 1; d < 16; d <<= 1) {
                s  += __shfl_xor(s, d);
                s2 += __shfl_xor(s2, d);
                mx  = fmaxf(mx, __shfl_xor(mx, d));
            }
            ssum[it][r] = s; ssq[it][r] = s2; smax[it][r] = mx;
        }
    if (l15 == 0) {
        #pragma unroll
        for (int it = 0; it < 2; ++it)
            #pragma unroll
            for (int r = 0; r < 4; ++r) {
                int i = it * 16 + q * 4 + r;
                red[w][i][0] = ssum[it][r];
                red[w][i][1] = ssq[it][r];
                red[w][i][2] = smax[it][r];
            }
    }
    __syncthreads();
    if (tid < 32) {
        float s  = red[0][tid][0] + red[1][tid][0] + red[2][tid][0] + red[3][tid][0];
        float s2 = red[0][tid][1] + red[1][tid][1] + red[2][tid][1] + red[3][tid][1];
        float mx = fmaxf(fmaxf(red[0][tid][2], red[1][tid][2]),
                         fmaxf(red[2][tid][2], red[3][tid][2]));
        float mu  = s * (1.f / 512.f);
        float var = fmaxf((s2 - s * mu) * (1.f / 511.f), 0.f);
        float sd  = sqrtf(var);
        rowM[tid]   = mx;
        rowInv[tid] = 1.f / (sd + 1e-6f);
    }
    __syncthreads();
    float dsum[2][4];
    #pragma unroll
    for (int it = 0; it < 2; ++it)
        #pragma unroll
        for (int r = 0; r < 4; ++r) {
            int i = it * 16 + q * 4 + r;
            float M = rowM[i], inv = rowInv[i];
            float s = 0.f;
            #pragma unroll
            for (int mt = 0; mt < 8; ++mt) {
                float e = __expf((acc[it][mt][r] - M) * inv);
                acc[it][mt][r] = e; s += e;
            }
            #pragma unroll
            for (int d = 1; d < 16; d <<= 1) s += __shfl_xor(s, d);
            dsum[it][r] = s;
        }
    if (l15 == 0) {
        #pragma unroll
        for (int it = 0; it < 2; ++it)
            #pragma unroll
            for (int r = 0; r < 4; ++r)
                red[w][it * 16 + q * 4 + r][0] = dsum[it][r];
    }
    __syncthreads();
    if (tid < 32)
        rowRden[tid] = 1.f / (red[0][tid][0] + red[1][tid][0] + red[2][tid][0] + red[3][tid][0]);
    __syncthreads();
    #pragma unroll
    for (int it = 0; it < 2; ++it)
        #pragma unroll
        for (int r = 0; r < 4; ++r) {
            int i = it * 16 + q * 4 + r;
            float rd = rowRden[i];
            #pragma unroll
            for (int mt = 0; mt < 8; ++mt) {
                int m = w * 128 + mt * 16 + l15;
                Ps[i * 520 + m] = f2bf(acc[it][mt][r] * rd);
            }
        }
    __syncthreads();   // Ps produced by all waves -> consumed by all waves

    // ---- Phase 4: O = P * Ve (V direct from global) + fused FC partial ----
    float fsum[4] = {0.f, 0.f, 0.f, 0.f};
    for (int h = 0; h < 2; ++h) {
        f32x4 oacc[2][8];
        #pragma unroll
        for (int it = 0; it < 2; ++it)
            #pragma unroll
            for (int dt = 0; dt < 8; ++dt)
                oacc[it][dt] = (f32x4){0.f, 0.f, 0.f, 0.f};
        const u16* vP = VT + (size_t)b * ND * NN
                      + (size_t)(h * 512 + wrow + l15) * NN + q * 8;
        for (int mc = 0; mc < 16; ++mc) {
            bf16x8 p0 = *(const bf16x8*)&Ps[l15 * 520 + mc * 32 + q * 8];
            bf16x8 p1 = *(const bf16x8*)&Ps[(16 + l15) * 520 + mc * 32 + q * 8];
            #pragma unroll
            for (int dt = 0; dt < 8; ++dt) {
                bf16x8 bf = *(const bf16x8*)(vP + (size_t)(dt * 16) * NN + mc * 32);
                oacc[0][dt] = __builtin_amdgcn_mfma_f32_16x16x32_bf16(p0, bf, oacc[0][dt], 0, 0, 0);
                oacc[1][dt] = __builtin_amdgcn_mfma_f32_16x16x32_bf16(p1, bf, oacc[1][dt], 0, 0, 0);
            }
        }
        // fused FC: out[b,c] += sum oacc[i,d] * fcw[c, i*D+d] (f32, no O round-trip)
        #pragma unroll
        for (int it = 0; it < 2; ++it) {
            #pragma unroll
            for (int r = 0; r < 4; ++r) {
                const int iglob = i0 + it * 16 + q * 4 + r;
                const float* fr = fcw + (size_t)iglob * ND + (h * 512 + wrow + l15);
                #pragma unroll
                for (int dt = 0; dt < 8; ++dt) {
                    float o = oacc[0][dt][r];
                    if (it == 1) o = oacc[1][dt][r];
                    fsum[0] += o * fr[dt * 16];
                    fsum[1] += o * fr[(size_t)NDW + dt * 16];
                    fsum[2] += o * fr[(size_t)2 * NDW + dt * 16];
                    fsum[3] += o * fr[(size_t)3 * NDW + dt * 16];
                }
            }
        }
    }
    // block-reduce fsum -> 4 atomics (red[] is free after the Ps barrier)
    #pragma unroll
    for (int c = 0; c < 4; ++c)
        #pragma unroll
        for (int d = 1; d < 64; d <<= 1)
            fsum[c] += __shfl_xor(fsum[c], d);
    if (lane == 0) {
        red[w][0][0] = fsum[0]; red[w][0][1] = fsum[1];
        red[w][0][2] = fsum[2]; red[w][0][3] = fsum[3];
    }
    __syncthreads();
    if (tid < 4) {
        float s = red[0][0][tid] + red[1][0][tid] + red[2][0][tid] + red[3][0][tid];
        atomicAdd(&out[b * 4 + tid], s);
    }
}

extern "C" void kernel_launch(void* const* d_in, const int* in_sizes, int n_in,
                              void* d_out, int out_size, void* d_ws, size_t ws_size,
                              hipStream_t stream) {
    (void)in_sizes; (void)n_in; (void)ws_size; (void)out_size;
    const float* Q   = (const float*)d_in[0];
    const float* K   = (const float*)d_in[1];
    const float* V   = (const float*)d_in[2];
    const int*   eid = (const int*)d_in[3];
    const float* emb = (const float*)d_in[4];
    const float* fcw = (const float*)d_in[15];
    const float* fcb = (const float*)d_in[16];
    float* out = (float*)d_out;

    u16* Qe = (u16*)d_ws;
    u16* Ke = Qe + (size_t)NBATCH * NN * ND;   // +64MB
    u16* VT = Ke + (size_t)NBATCH * NN * ND;   // +64MB (total ws use: 192MB)

    nma_init_out<<<dim3(1), dim3(256), 0, stream>>>(out, fcb);
    prep_qk<<<dim3(16384), dim3(256), 0, stream>>>(Q, K, eid, emb, Qe, Ke);
    prep_vt<<<dim3(8, 16, 64), dim3(256), 0, stream>>>(V, eid, emb, VT);
    nma_attn<<<dim3(1024), dim3(256), 0, stream>>>(Qe, Ke, VT, fcw, out);
}

// Round 3
// 790.336 us; speedup vs baseline: 1.0140x; 1.0140x over previous
//
#include <hip/hip_runtime.h>

#define NN 512
#define ND 1024
#define NDW 524288   // N*D
#define NBATCH 64

typedef __attribute__((ext_vector_type(8))) __bf16 bf16x8;
typedef __attribute__((ext_vector_type(4))) float f32x4;
typedef unsigned short u16;
typedef unsigned int u32;

__device__ __forceinline__ u16 f2bf(float x) {
    u32 u = __float_as_uint(x);
    u = (u + 0x7fffu + ((u >> 16) & 1u)) >> 16;   // RNE
    return (u16)u;
}

// Fused prep: blocks [0,16384) build Qe/Ke, [16384,24576) build VT,
// block 24576 inits out=fcb. One launch instead of three.
__global__ __launch_bounds__(256)
void prep_all(const float* __restrict__ Q, const float* __restrict__ K,
              const float* __restrict__ V, const int* __restrict__ eid,
              const float* __restrict__ emb,
              u16* __restrict__ Qe, u16* __restrict__ Ke, u16* __restrict__ VT,
              float* __restrict__ out, const float* __restrict__ fcb)
{
    __shared__ u16 T[64 * 72];
    const int bb = blockIdx.x;
    const int tid = threadIdx.x;

    if (bb < 16384) {
        // ---- Qe = bf16(Q+emb[eid]), Ke = bf16(K+emb[eid]) ----
        size_t f = ((size_t)bb * 256 + tid) * 8;
        int n = (int)((f >> 10) & (NN - 1));
        int col = (int)(f & (ND - 1));
        const float* ep = emb + (size_t)eid[n] * ND + col;
        float4 e0 = *(const float4*)ep, e1 = *(const float4*)(ep + 4);
        {
            const float* qp = Q + f;
            float4 x0 = *(const float4*)qp, x1 = *(const float4*)(qp + 4);
            union { uint4 u; u16 s[8]; } o;
            o.s[0]=f2bf(x0.x+e0.x); o.s[1]=f2bf(x0.y+e0.y); o.s[2]=f2bf(x0.z+e0.z); o.s[3]=f2bf(x0.w+e0.w);
            o.s[4]=f2bf(x1.x+e1.x); o.s[5]=f2bf(x1.y+e1.y); o.s[6]=f2bf(x1.z+e1.z); o.s[7]=f2bf(x1.w+e1.w);
            *(uint4*)(Qe + f) = o.u;
        }
        {
            const float* kp = K + f;
            float4 x0 = *(const float4*)kp, x1 = *(const float4*)(kp + 4);
            union { uint4 u; u16 s[8]; } o;
            o.s[0]=f2bf(x0.x+e0.x); o.s[1]=f2bf(x0.y+e0.y); o.s[2]=f2bf(x0.z+e0.z); o.s[3]=f2bf(x0.w+e0.w);
            o.s[4]=f2bf(x1.x+e1.x); o.s[5]=f2bf(x1.y+e1.y); o.s[6]=f2bf(x1.z+e1.z); o.s[7]=f2bf(x1.w+e1.w);
            *(uint4*)(Ke + f) = o.u;
        }
    } else if (bb < 16384 + 8192) {
        // ---- VT[b,d,n] = bf16(V[b,n,d] + emb[eid[n],d]) via 64x64 LDS transpose ----
        const int t = bb - 16384;
        const int n0 = (t & 7) * 64, d0 = ((t >> 3) & 15) * 64, b = t >> 7;
        {
            const int r = tid >> 2, cs = (tid & 3) * 16;
            const int n = n0 + r;
            const float* vp = V + ((size_t)b * NN + n) * ND + d0 + cs;
            const float* ep = emb + (size_t)eid[n] * ND + d0 + cs;
            #pragma unroll
            for (int j = 0; j < 4; ++j) {
                float4 v = *(const float4*)(vp + j * 4);
                float4 e = *(const float4*)(ep + j * 4);
                T[(cs + j*4 + 0) * 72 + r] = f2bf(v.x + e.x);
                T[(cs + j*4 + 1) * 72 + r] = f2bf(v.y + e.y);
                T[(cs + j*4 + 2) * 72 + r] = f2bf(v.z + e.z);
                T[(cs + j*4 + 3) * 72 + r] = f2bf(v.w + e.w);
            }
        }
        __syncthreads();
        {
            const int dr = tid >> 2, ms = (tid & 3) * 16;
            u16* dst = VT + ((size_t)b * ND + d0 + dr) * NN + n0 + ms;
            *(uint4*)dst       = *(const uint4*)&T[dr * 72 + ms];
            *(uint4*)(dst + 8) = *(const uint4*)&T[dr * 72 + ms + 8];
        }
    } else {
        if (tid < NBATCH * 4) out[tid] = fcb[tid & 3];
    }
}

// One block per (b, 32-row Q tile). Dead-path: neuromod term is per-row const,
// cancels in (ms-mean)/std -> only QK^T -> z-softmax -> PV -> FC survives.
// XCD swizzle: b = (bid&7) + 8*(bid>>7) so all 16 tiles of a batch share an XCD L2.
//
// DIRECT-REGISTER operands: wave w's MFMA B-rows (Ke/VT rows [w*128,w*128+128))
// are wave-private; the fragment shape (16 rows x 16B) is exactly one
// global_load_dwordx4. No LDS staging, no barriers in the K-loops.
// NOTE: plain __launch_bounds__(256) — NO min-waves arg. (256,3) capped VGPRs
// at 84 and spilled ~130 regs/thread to scratch (R2: +136MB write, +136MB read,
// 397us). Register demand here is ~200+; needs the full 256-reg budget.
// FC is fused into the epilogue from the f32 oacc (no O materialization).
__global__ __launch_bounds__(256)
void nma_attn(const u16* __restrict__ Qe, const u16* __restrict__ Ke,
              const u16* __restrict__ VT, const float* __restrict__ fcw,
              float* __restrict__ out)
{
    __shared__ __align__(16) u16 Ps[32 * 520];    // probs bf16
    __shared__ float red[4][32][4];
    __shared__ float rowM[32], rowInv[32], rowRden[32];

    const int tid  = threadIdx.x;
    const int w    = tid >> 6;
    const int lane = tid & 63;
    const int q    = lane >> 4;
    const int l15  = lane & 15;
    const int bid  = blockIdx.x;
    const int jj   = bid >> 3;
    const int b    = (bid & 7) + ((jj >> 4) << 3);
    const int i0   = (jj & 15) * 32;
    const size_t bOff = (size_t)b * NN * ND;
    const int wrow = w * 128;     // wave-private B-operand row base

    f32x4 acc[2][8];
    #pragma unroll
    for (int it = 0; it < 2; ++it)
        #pragma unroll
        for (int mt = 0; mt < 8; ++mt)
            acc[it][mt] = (f32x4){0.f, 0.f, 0.f, 0.f};

    // ---- Phase 2: S = Qe * Ke^T (all operands direct from global) ----
    {
        const u16* aP0 = Qe + bOff + (size_t)(i0 + l15) * ND + q * 8;
        const u16* aP1 = aP0 + (size_t)16 * ND;
        const u16* bP  = Ke + bOff + (size_t)(wrow + l15) * ND + q * 8;
        for (int kc = 0; kc < 32; ++kc) {
            const int ko = kc * 32;
            bf16x8 a0 = *(const bf16x8*)(aP0 + ko);
            bf16x8 a1 = *(const bf16x8*)(aP1 + ko);
            #pragma unroll
            for (int mt = 0; mt < 8; ++mt) {
                bf16x8 bf = *(const bf16x8*)(bP + (size_t)(mt * 16) * ND + ko);
                acc[0][mt] = __builtin_amdgcn_mfma_f32_16x16x32_bf16(a0, bf, acc[0][mt], 0, 0, 0);
                acc[1][mt] = __builtin_amdgcn_mfma_f32_16x16x32_bf16(a1, bf, acc[1][mt], 0, 0, 0);
            }
        }
    }

    // ---- Phase 3: exact row stats (mean, ddof=1 std, max), softmax(z) ----
    const float SC = 0.03125f;
    #pragma unroll
    for (int it = 0; it < 2; ++it)
        #pragma unroll
        for (int mt = 0; mt < 8; ++mt) {
            acc[it][mt][0] *= SC; acc[it][mt][1] *= SC;
            acc[it][mt][2] *= SC; acc[it][mt][3] *= SC;
        }
    float ssum[2][4], ssq[2][4], smax[2][4];
    #pragma unroll
    for (int it = 0; it < 2; ++it)
        #pragma unroll
        for (int r = 0; r < 4; ++r) {
            float s = 0.f, s2 = 0.f, mx = -3.4e38f;
            #pragma unroll
            for (int mt = 0; mt < 8; ++mt) {
                float v = acc[it][mt][r];
                s += v; s2 += v * v; mx = fmaxf(mx, v);
            }
            #pragma unroll
            for (int d = 1; d < 16; d <<= 1) {
                s  += __shfl_xor(s, d);
                s2 += __shfl_xor(s2, d);
                mx  = fmaxf(mx, __shfl_xor(mx, d));
            }
            ssum[it][r] = s; ssq[it][r] = s2; smax[it][r] = mx;
        }
    if (l15 == 0) {
        #pragma unroll
        for (int it = 0; it < 2; ++it)
            #pragma unroll
            for (int r = 0; r < 4; ++r) {
                int i = it * 16 + q * 4 + r;
                red[w][i][0] = ssum[it][r];
                red[w][i][1] = ssq[it][r];
                red[w][i][2] = smax[it][r];
            }
    }
    __syncthreads();
    if (tid < 32) {
        float s  = red[0][tid][0] + red[1][tid][0] + red[2][tid][0] + red[3][tid][0];
        float s2 = red[0][tid][1] + red[1][tid][1] + red[2][tid][1] + red[3][tid][1];
        float mx = fmaxf(fmaxf(red[0][tid][2], red[1][tid][2]),
                         fmaxf(red[2][tid][2], red[3][tid][2]));
        float mu  = s * (1.f / 512.f);
        float var = fmaxf((s2 - s * mu) * (1.f / 511.f), 0.f);
        float sd  = sqrtf(var);
        rowM[tid]   = mx;
        rowInv[tid] = 1.f / (sd + 1e-6f);
    }
    __syncthreads();
    float dsum[2][4];
    #pragma unroll
    for (int it = 0; it < 2; ++it)
        #pragma unroll
        for (int r = 0; r < 4; ++r) {
            int i = it * 16 + q * 4 + r;
            float M = rowM[i], inv = rowInv[i];
            float s = 0.f;
            #pragma unroll
            for (int mt = 0; mt < 8; ++mt) {
                float e = __expf((acc[it][mt][r] - M) * inv);
                acc[it][mt][r] = e; s += e;
            }
            #pragma unroll
            for (int d = 1; d < 16; d <<= 1) s += __shfl_xor(s, d);
            dsum[it][r] = s;
        }
    if (l15 == 0) {
        #pragma unroll
        for (int it = 0; it < 2; ++it)
            #pragma unroll
            for (int r = 0; r < 4; ++r)
                red[w][it * 16 + q * 4 + r][0] = dsum[it][r];
    }
    __syncthreads();
    if (tid < 32)
        rowRden[tid] = 1.f / (red[0][tid][0] + red[1][tid][0] + red[2][tid][0] + red[3][tid][0]);
    __syncthreads();
    #pragma unroll
    for (int it = 0; it < 2; ++it)
        #pragma unroll
        for (int r = 0; r < 4; ++r) {
            int i = it * 16 + q * 4 + r;
            float rd = rowRden[i];
            #pragma unroll
            for (int mt = 0; mt < 8; ++mt) {
                int m = w * 128 + mt * 16 + l15;
                Ps[i * 520 + m] = f2bf(acc[it][mt][r] * rd);
            }
        }
    __syncthreads();   // Ps produced by all waves -> consumed by all waves

    // ---- Phase 4: O = P * Ve (V direct from global) + fused FC partial ----
    float fsum[4] = {0.f, 0.f, 0.f, 0.f};
    for (int h = 0; h < 2; ++h) {
        f32x4 oacc[2][8];
        #pragma unroll
        for (int it = 0; it < 2; ++it)
            #pragma unroll
            for (int dt = 0; dt < 8; ++dt)
                oacc[it][dt] = (f32x4){0.f, 0.f, 0.f, 0.f};
        const u16* vP = VT + (size_t)b * ND * NN
                      + (size_t)(h * 512 + wrow + l15) * NN + q * 8;
        for (int mc = 0; mc < 16; ++mc) {
            bf16x8 p0 = *(const bf16x8*)&Ps[l15 * 520 + mc * 32 + q * 8];
            bf16x8 p1 = *(const bf16x8*)&Ps[(16 + l15) * 520 + mc * 32 + q * 8];
            #pragma unroll
            for (int dt = 0; dt < 8; ++dt) {
                bf16x8 bf = *(const bf16x8*)(vP + (size_t)(dt * 16) * NN + mc * 32);
                oacc[0][dt] = __builtin_amdgcn_mfma_f32_16x16x32_bf16(p0, bf, oacc[0][dt], 0, 0, 0);
                oacc[1][dt] = __builtin_amdgcn_mfma_f32_16x16x32_bf16(p1, bf, oacc[1][dt], 0, 0, 0);
            }
        }
        // fused FC: out[b,c] += sum oacc[it][dt][r] * fcw[c, iglob*D + d]
        #pragma unroll
        for (int it = 0; it < 2; ++it) {
            #pragma unroll
            for (int r = 0; r < 4; ++r) {
                const int iglob = i0 + it * 16 + q * 4 + r;
                const float* fr = fcw + (size_t)iglob * ND + (h * 512 + wrow + l15);
                #pragma unroll
                for (int dt = 0; dt < 8; ++dt) {
                    const float o = oacc[it][dt][r];
                    fsum[0] += o * fr[dt * 16];
                    fsum[1] += o * fr[(size_t)NDW + dt * 16];
                    fsum[2] += o * fr[(size_t)2 * NDW + dt * 16];
                    fsum[3] += o * fr[(size_t)3 * NDW + dt * 16];
                }
            }
        }
    }
    // block-reduce fsum -> 4 atomics (red[] is free after the Ps barrier)
    #pragma unroll
    for (int c = 0; c < 4; ++c)
        #pragma unroll
        for (int d = 1; d < 64; d <<= 1)
            fsum[c] += __shfl_xor(fsum[c], d);
    if (lane == 0) {
        red[w][0][0] = fsum[0]; red[w][0][1] = fsum[1];
        red[w][0][2] = fsum[2]; red[w][0][3] = fsum[3];
    }
    __syncthreads();
    if (tid < 4) {
        float s = red[0][0][tid] + red[1][0][tid] + red[2][0][tid] + red[3][0][tid];
        atomicAdd(&out[b * 4 + tid], s);
    }
}

extern "C" void kernel_launch(void* const* d_in, const int* in_sizes, int n_in,
                              void* d_out, int out_size, void* d_ws, size_t ws_size,
                              hipStream_t stream) {
    (void)in_sizes; (void)n_in; (void)ws_size; (void)out_size;
    const float* Q   = (const float*)d_in[0];
    const float* K   = (const float*)d_in[1];
    const float* V   = (const float*)d_in[2];
    const int*   eid = (const int*)d_in[3];
    const float* emb = (const float*)d_in[4];
    const float* fcw = (const float*)d_in[15];
    const float* fcb = (const float*)d_in[16];
    float* out = (float*)d_out;

    u16* Qe = (u16*)d_ws;
    u16* Ke = Qe + (size_t)NBATCH * NN * ND;   // +64MB
    u16* VT = Ke + (size_t)NBATCH * NN * ND;   // +64MB (total ws use: 192MB)

    prep_all<<<dim3(16384 + 8192 + 1), dim3(256), 0, stream>>>(
        Q, K, V, eid, emb, Qe, Ke, VT, out, fcb);
    nma_attn<<<dim3(1024), dim3(256), 0, stream>>>(Qe, Ke, VT, fcw, out);
}

// Round 6
// 717.169 us; speedup vs baseline: 1.1174x; 1.1020x over previous
//
#include <hip/hip_runtime.h>

#define NN 512
#define ND 1024
#define NDW 524288   // N*D
#define NBATCH 64

typedef __attribute__((ext_vector_type(8))) __bf16 bf16x8;
typedef __attribute__((ext_vector_type(4))) float f32x4;
typedef unsigned short u16;
typedef unsigned int u32;

__device__ __forceinline__ u16 f2bf(float x) {
    u32 u = __float_as_uint(x);
    u = (u + 0x7fffu + ((u >> 16) & 1u)) >> 16;   // RNE
    return (u16)u;
}

union BF8 { bf16x8 v; u16 s[8]; };

// async global->LDS DMA, 16B per lane; LDS dest = wave-uniform base + lane*16
__device__ __forceinline__ void dma16(const u16* g, const u16* l) {
    __builtin_amdgcn_global_load_lds(
        (const __attribute__((address_space(1))) u32*)(uintptr_t)g,
        (__attribute__((address_space(3))) u32*)(u32)(uintptr_t)l,
        16, 0, 0);
}

// Fused prep: blocks [0,16384) build Ke, [16384,24576) build VT,
// block 24576 inits out=fcb. NO Qe stream: Q has zero cross-block reuse,
// attn converts it in-register.
__global__ __launch_bounds__(256)
void prep_all(const float* __restrict__ K, const float* __restrict__ V,
              const int* __restrict__ eid, const float* __restrict__ emb,
              u16* __restrict__ Ke, u16* __restrict__ VT,
              float* __restrict__ out, const float* __restrict__ fcb)
{
    __shared__ u16 T[64 * 72];
    const int bb = blockIdx.x;
    const int tid = threadIdx.x;

    if (bb < 16384) {
        // ---- Ke = bf16(K + emb[eid]) row-major [B,N,D] ----
        size_t f = ((size_t)bb * 256 + tid) * 8;
        int n = (int)((f >> 10) & (NN - 1));
        int col = (int)(f & (ND - 1));
        const float* ep = emb + (size_t)eid[n] * ND + col;
        float4 e0 = *(const float4*)ep, e1 = *(const float4*)(ep + 4);
        const float* kp = K + f;
        float4 x0 = *(const float4*)kp, x1 = *(const float4*)(kp + 4);
        union { uint4 u; u16 s[8]; } o;
        o.s[0]=f2bf(x0.x+e0.x); o.s[1]=f2bf(x0.y+e0.y); o.s[2]=f2bf(x0.z+e0.z); o.s[3]=f2bf(x0.w+e0.w);
        o.s[4]=f2bf(x1.x+e1.x); o.s[5]=f2bf(x1.y+e1.y); o.s[6]=f2bf(x1.z+e1.z); o.s[7]=f2bf(x1.w+e1.w);
        *(uint4*)(Ke + f) = o.u;
    } else if (bb < 16384 + 8192) {
        // ---- VT[b,d,n] = bf16(V[b,n,d] + emb[eid[n],d]) via 64x64 LDS transpose ----
        const int t = bb - 16384;
        const int n0 = (t & 7) * 64, d0 = ((t >> 3) & 15) * 64, b = t >> 7;
        {
            const int r = tid >> 2, cs = (tid & 3) * 16;
            const int n = n0 + r;
            const float* vp = V + ((size_t)b * NN + n) * ND + d0 + cs;
            const float* ep = emb + (size_t)eid[n] * ND + d0 + cs;
            #pragma unroll
            for (int j = 0; j < 4; ++j) {
                float4 v = *(const float4*)(vp + j * 4);
                float4 e = *(const float4*)(ep + j * 4);
                T[(cs + j*4 + 0) * 72 + r] = f2bf(v.x + e.x);
                T[(cs + j*4 + 1) * 72 + r] = f2bf(v.y + e.y);
                T[(cs + j*4 + 2) * 72 + r] = f2bf(v.z + e.z);
                T[(cs + j*4 + 3) * 72 + r] = f2bf(v.w + e.w);
            }
        }
        __syncthreads();
        {
            const int dr = tid >> 2, ms = (tid & 3) * 16;
            u16* dst = VT + ((size_t)b * ND + d0 + dr) * NN + n0 + ms;
            *(uint4*)dst       = *(const uint4*)&T[dr * 72 + ms];
            *(uint4*)(dst + 8) = *(const uint4*)&T[dr * 72 + ms + 8];
        }
    } else {
        if (tid < NBATCH * 4) out[tid] = fcb[tid & 3];
    }
}

// One block per (b, 32-row Q tile). Dead-path: neuromod term is per-row const,
// cancels in (ms-mean)/std -> only QK^T -> z-softmax -> PV -> FC survives.
// XCD swizzle: b = (bid&7) + 8*(bid>>7) so all 16 tiles of a batch share an XCD L2.
//
// Barrier-free LDS-DMA pipeline, ORDER-ROBUST variant. Wave w owns KV rows
// [w*128,w*128+128): DMA and reads are wave-private -> no __syncthreads in the
// K-loops. ALL waits are s_waitcnt vmcnt(0)/lgkmcnt(0): correctness no longer
// depends on the compiler's vmem issue order. (R1-R5 lesson: the counted
// vmcnt(8) contract assumed FIFO = [DMA x8][Q-loads x8]; the scheduler may
// legally swap them -> stale-KV race that appears/disappears with codegen.
// R1 passed by luck; R4/R5 failed. vmcnt(0) is schedule-independent.)
// Pipeline cover is kept: DMA(KC+1) + Q(KC+1) loads issue after the KV-read
// drain and fly across MFMA(KC) + f2bf(KC+1); the drain at iter KC+1's head
// then costs ~0 extra.
// FC fused into the epilogue from f32 oacc (no O buffer, no fc_red).
// Plain __launch_bounds__(256): (256,3) caused a 130-reg spill in R2.
__global__ __launch_bounds__(256)
void nma_attn(const float* __restrict__ Q, const int* __restrict__ eid,
              const float* __restrict__ emb, const u16* __restrict__ Ke,
              const u16* __restrict__ VT, const float* __restrict__ fcw,
              float* __restrict__ out)
{
    __shared__ __align__(16) u16 KV[NN * 32];     // 32KB chunk [512 rows][32 cols] bf16
    __shared__ __align__(16) u16 Ps[32 * 520];    // probs bf16
    __shared__ float red[4][32][4];
    __shared__ float rowM[32], rowInv[32], rowRden[32];

    const int tid  = threadIdx.x;
    const int w    = tid >> 6;
    const int lane = tid & 63;
    const int q    = lane >> 4;
    const int l15  = lane & 15;
    const int rr   = lane >> 2;   // DMA: row-within-16
    const int seg  = lane & 3;    // DMA: 16B granule within 64B row
    const int bid  = blockIdx.x;
    const int jj   = bid >> 3;
    const int b    = (bid & 7) + ((jj >> 4) << 3);
    const int i0   = (jj & 15) * 32;
    const size_t bOff = (size_t)b * NN * ND;
    const int wrow = w * 128;     // wave-private KV row base

    const float* Qr0 = Q + bOff + (size_t)(i0 + l15) * ND;
    const float* Qr1 = Q + bOff + (size_t)(i0 + 16 + l15) * ND;
    const float* Er0 = emb + (size_t)eid[i0 + l15] * ND;
    const float* Er1 = emb + (size_t)eid[i0 + 16 + l15] * ND;

    const u16* KeB = Ke + bOff;
    const u16* VTB = VT + (size_t)b * ND * NN;

#define DMA_KE(KC) do {                                                         \
    _Pragma("unroll")                                                           \
    for (int ii_ = 0; ii_ < 8; ++ii_)                                           \
        dma16(KeB + (size_t)(wrow + ii_ * 16 + rr) * ND + (KC) * 32 + seg * 8,  \
              &KV[(wrow + ii_ * 16) * 32]);                                     \
    } while (0)

#define DMA_VT(H, MC) do {                                                      \
    _Pragma("unroll")                                                           \
    for (int ii_ = 0; ii_ < 8; ++ii_)                                           \
        dma16(VTB + (size_t)((H) * 512 + wrow + ii_ * 16 + rr) * NN             \
                  + (MC) * 32 + seg * 8,                                        \
              &KV[(wrow + ii_ * 16) * 32]);                                     \
    } while (0)

#define LOADQ(DST, KOFF) do {                                                   \
    DST[0] = *(const float4*)(Qr0 + (KOFF));                                    \
    DST[1] = *(const float4*)(Qr0 + (KOFF) + 4);                                \
    DST[2] = *(const float4*)(Er0 + (KOFF));                                    \
    DST[3] = *(const float4*)(Er0 + (KOFF) + 4);                                \
    DST[4] = *(const float4*)(Qr1 + (KOFF));                                    \
    DST[5] = *(const float4*)(Qr1 + (KOFF) + 4);                                \
    DST[6] = *(const float4*)(Er1 + (KOFF));                                    \
    DST[7] = *(const float4*)(Er1 + (KOFF) + 4);                                \
    } while (0)

    f32x4 acc[2][8];
    #pragma unroll
    for (int it = 0; it < 2; ++it)
        #pragma unroll
        for (int mt = 0; mt < 8; ++mt)
            acc[it][mt] = (f32x4){0.f, 0.f, 0.f, 0.f};

    // ---- Phase 2: S = Qe * Ke^T (barrier-free, order-robust pipeline) ----
    float4 cur[8], nxt[8];
    {   // prologue: chunk-0 Q loads + chunk-0 DMA; both drained at iter 0's head
        LOADQ(cur, q * 8);
        DMA_KE(0);
    }

#define P2BODY(KC, CUR, NXT) do {                                               \
    asm volatile("s_waitcnt vmcnt(0)" ::: "memory"); /* DMA(KC)+Q(KC) done */   \
    bf16x8 bfr[8];                                                              \
    _Pragma("unroll")                                                           \
    for (int mt = 0; mt < 8; ++mt)                                              \
        bfr[mt] = *(const bf16x8*)&KV[(wrow + mt * 16 + l15) * 32 + q * 8];     \
    BF8 a0u, a1u;                                                               \
    a0u.s[0]=f2bf(CUR[0].x+CUR[2].x); a0u.s[1]=f2bf(CUR[0].y+CUR[2].y);         \
    a0u.s[2]=f2bf(CUR[0].z+CUR[2].z); a0u.s[3]=f2bf(CUR[0].w+CUR[2].w);         \
    a0u.s[4]=f2bf(CUR[1].x+CUR[3].x); a0u.s[5]=f2bf(CUR[1].y+CUR[3].y);         \
    a0u.s[6]=f2bf(CUR[1].z+CUR[3].z); a0u.s[7]=f2bf(CUR[1].w+CUR[3].w);         \
    a1u.s[0]=f2bf(CUR[4].x+CUR[6].x); a1u.s[1]=f2bf(CUR[4].y+CUR[6].y);         \
    a1u.s[2]=f2bf(CUR[4].z+CUR[6].z); a1u.s[3]=f2bf(CUR[4].w+CUR[6].w);         \
    a1u.s[4]=f2bf(CUR[5].x+CUR[7].x); a1u.s[5]=f2bf(CUR[5].y+CUR[7].y);         \
    a1u.s[6]=f2bf(CUR[5].z+CUR[7].z); a1u.s[7]=f2bf(CUR[5].w+CUR[7].w);         \
    asm volatile("s_waitcnt lgkmcnt(0)" ::: "memory"); /* KV reads in regs */   \
    if ((KC) < 31) {                                                            \
        DMA_KE((KC) + 1);                 /* overwrite safe: reads drained */   \
        LOADQ(NXT, ((KC) + 1) * 32 + q * 8); /* flies across MFMA block */      \
    }                                                                           \
    _Pragma("unroll")                                                           \
    for (int mt = 0; mt < 8; ++mt) {                                            \
        acc[0][mt] = __builtin_amdgcn_mfma_f32_16x16x32_bf16(a0u.v, bfr[mt], acc[0][mt], 0, 0, 0); \
        acc[1][mt] = __builtin_amdgcn_mfma_f32_16x16x32_bf16(a1u.v, bfr[mt], acc[1][mt], 0, 0, 0); \
    } } while (0)

    for (int kc = 0; kc < 32; kc += 2) {
        P2BODY(kc, cur, nxt);
        P2BODY(kc + 1, nxt, cur);
    }

    // ---- Phase 3: exact row stats (mean, ddof=1 std, max), softmax(z) ----
    const float SC = 0.03125f;
    #pragma unroll
    for (int it = 0; it < 2; ++it)
        #pragma unroll
        for (int mt = 0; mt < 8; ++mt) {
            acc[it][mt][0] *= SC; acc[it][mt][1] *= SC;
            acc[it][mt][2] *= SC; acc[it][mt][3] *= SC;
        }
    float ssum[2][4], ssq[2][4], smax[2][4];
    #pragma unroll
    for (int it = 0; it < 2; ++it)
        #pragma unroll
        for (int r = 0; r < 4; ++r) {
            float s = 0.f, s2 = 0.f, mx = -3.4e38f;
            #pragma unroll
            for (int mt = 0; mt < 8; ++mt) {
                float v = acc[it][mt][r];
                s += v; s2 += v * v; mx = fmaxf(mx, v);
            }
            #pragma unroll
            for (int d = 1; d < 16; d <<= 1) {
                s  += __shfl_xor(s, d);
                s2 += __shfl_xor(s2, d);
                mx  = fmaxf(mx, __shfl_xor(mx, d));
            }
            ssum[it][r] = s; ssq[it][r] = s2; smax[it][r] = mx;
        }
    if (l15 == 0) {
        #pragma unroll
        for (int it = 0; it < 2; ++it)
            #pragma unroll
            for (int r = 0; r < 4; ++r) {
                int i = it * 16 + q * 4 + r;
                red[w][i][0] = ssum[it][r];
                red[w][i][1] = ssq[it][r];
                red[w][i][2] = smax[it][r];
            }
    }
    __syncthreads();
    if (tid < 32) {
        float s  = red[0][tid][0] + red[1][tid][0] + red[2][tid][0] + red[3][tid][0];
        float s2 = red[0][tid][1] + red[1][tid][1] + red[2][tid][1] + red[3][tid][1];
        float mx = fmaxf(fmaxf(red[0][tid][2], red[1][tid][2]),
                         fmaxf(red[2][tid][2], red[3][tid][2]));
        float mu  = s * (1.f / 512.f);
        float var = fmaxf((s2 - s * mu) * (1.f / 511.f), 0.f);
        float sd  = sqrtf(var);
        rowM[tid]   = mx;
        rowInv[tid] = 1.f / (sd + 1e-6f);
    }
    __syncthreads();
    float dsum[2][4];
    #pragma unroll
    for (int it = 0; it < 2; ++it)
        #pragma unroll
        for (int r = 0; r < 4; ++r) {
            int i = it * 16 + q * 4 + r;
            float M = rowM[i], inv = rowInv[i];
            float s = 0.f;
            #pragma unroll
            for (int mt = 0; mt < 8; ++mt) {
                float e = __expf((acc[it][mt][r] - M) * inv);
                acc[it][mt][r] = e; s += e;
            }
            #pragma unroll
            for (int d = 1; d < 16; d <<= 1) s += __shfl_xor(s, d);
            dsum[it][r] = s;
        }
    if (l15 == 0) {
        #pragma unroll
        for (int it = 0; it < 2; ++it)
            #pragma unroll
            for (int r = 0; r < 4; ++r)
                red[w][it * 16 + q * 4 + r][0] = dsum[it][r];
    }
    __syncthreads();
    if (tid < 32)
        rowRden[tid] = 1.f / (red[0][tid][0] + red[1][tid][0] + red[2][tid][0] + red[3][tid][0]);
    __syncthreads();
    #pragma unroll
    for (int it = 0; it < 2; ++it)
        #pragma unroll
        for (int r = 0; r < 4; ++r) {
            int i = it * 16 + q * 4 + r;
            float rd = rowRden[i];
            #pragma unroll
            for (int mt = 0; mt < 8; ++mt) {
                int m = w * 128 + mt * 16 + l15;
                Ps[i * 520 + m] = f2bf(acc[it][mt][r] * rd);
            }
        }
    __syncthreads();   // Ps produced by all waves -> consumed by all waves

    // ---- Phase 4: O = P * Ve (barrier-free, all-vmcnt(0)) + fused FC ----
    DMA_VT(0, 0);      // right after the barrier; drained by first vmcnt(0)
    float fsum[4] = {0.f, 0.f, 0.f, 0.f};
    for (int h = 0; h < 2; ++h) {
        f32x4 oacc[2][8];
        #pragma unroll
        for (int it = 0; it < 2; ++it)
            #pragma unroll
            for (int dt = 0; dt < 8; ++dt)
                oacc[it][dt] = (f32x4){0.f, 0.f, 0.f, 0.f};
        for (int mc = 0; mc < 16; ++mc) {
            // P reads are DMA-independent: issue them before the vmcnt stall
            bf16x8 p0 = *(const bf16x8*)&Ps[l15 * 520 + mc * 32 + q * 8];
            bf16x8 p1 = *(const bf16x8*)&Ps[(16 + l15) * 520 + mc * 32 + q * 8];
            asm volatile("s_waitcnt vmcnt(0)" ::: "memory");  // chunk ready
            bf16x8 bfr[8];
            #pragma unroll
            for (int dt = 0; dt < 8; ++dt)
                bfr[dt] = *(const bf16x8*)&KV[(wrow + dt * 16 + l15) * 32 + q * 8];
            asm volatile("s_waitcnt lgkmcnt(0)" ::: "memory");
            const int j = h * 16 + mc;
            if (j < 31) {
                const int jn = j + 1;
                DMA_VT(jn >> 4, jn & 15);   // overlap next chunk with MFMA
            }
            #pragma unroll
            for (int dt = 0; dt < 8; ++dt) {
                oacc[0][dt] = __builtin_amdgcn_mfma_f32_16x16x32_bf16(p0, bfr[dt], oacc[0][dt], 0, 0, 0);
                oacc[1][dt] = __builtin_amdgcn_mfma_f32_16x16x32_bf16(p1, bfr[dt], oacc[1][dt], 0, 0, 0);
            }
        }
        // fused FC: out[b,c] += sum oacc[it][dt][r] * fcw[c, iglob*D + dglob]
        #pragma unroll
        for (int it = 0; it < 2; ++it) {
            #pragma unroll
            for (int r = 0; r < 4; ++r) {
                const int iglob = i0 + it * 16 + q * 4 + r;
                const float* fr = fcw + (size_t)iglob * ND + (h * 512 + wrow + l15);
                #pragma unroll
                for (int dt = 0; dt < 8; ++dt) {
                    const float o = oacc[it][dt][r];
                    fsum[0] += o * fr[dt * 16];
                    fsum[1] += o * fr[(size_t)NDW + dt * 16];
                    fsum[2] += o * fr[(size_t)2 * NDW + dt * 16];
                    fsum[3] += o * fr[(size_t)3 * NDW + dt * 16];
                }
            }
        }
    }
    // block-reduce fsum -> 4 atomics (red[] is free after the Ps barrier)
    #pragma unroll
    for (int c = 0; c < 4; ++c)
        #pragma unroll
        for (int d = 1; d < 64; d <<= 1)
            fsum[c] += __shfl_xor(fsum[c], d);
    if (lane == 0) {
        red[w][0][0] = fsum[0]; red[w][0][1] = fsum[1];
        red[w][0][2] = fsum[2]; red[w][0][3] = fsum[3];
    }
    __syncthreads();
    if (tid < 4) {
        float s = red[0][0][tid] + red[1][0][tid] + red[2][0][tid] + red[3][0][tid];
        atomicAdd(&out[b * 4 + tid], s);
    }
#undef P2BODY
#undef LOADQ
#undef DMA_KE
#undef DMA_VT
}

extern "C" void kernel_launch(void* const* d_in, const int* in_sizes, int n_in,
                              void* d_out, int out_size, void* d_ws, size_t ws_size,
                              hipStream_t stream) {
    (void)in_sizes; (void)n_in; (void)ws_size; (void)out_size;
    const float* Q   = (const float*)d_in[0];
    const float* K   = (const float*)d_in[1];
    const float* V   = (const float*)d_in[2];
    const int*   eid = (const int*)d_in[3];
    const float* emb = (const float*)d_in[4];
    const float* fcw = (const float*)d_in[15];
    const float* fcb = (const float*)d_in[16];
    float* out = (float*)d_out;

    u16* Ke = (u16*)d_ws;
    u16* VT = Ke + (size_t)NBATCH * NN * ND;   // +64MB (total ws use: 128MB)

    prep_all<<<dim3(16384 + 8192 + 1), dim3(256), 0, stream>>>(
        K, V, eid, emb, Ke, VT, out, fcb);
    nma_attn<<<dim3(1024), dim3(256), 0, stream>>>(Q, eid, emb, Ke, VT, fcw, out);
}

// Round 7
// 681.432 us; speedup vs baseline: 1.1760x; 1.0524x over previous
//
#include <hip/hip_runtime.h>

#define NN 512
#define ND 1024
#define NDW 524288   // N*D
#define NBATCH 64

typedef __attribute__((ext_vector_type(8))) __bf16 bf16x8;
typedef __attribute__((ext_vector_type(4))) float f32x4;
typedef unsigned short u16;
typedef unsigned int u32;

__device__ __forceinline__ u16 f2bf(float x) {
    u32 u = __float_as_uint(x);
    u = (u + 0x7fffu + ((u >> 16) & 1u)) >> 16;   // RNE
    return (u16)u;
}

// async global->LDS DMA, 16B per lane; LDS dest = wave-uniform base + lane*16
__device__ __forceinline__ void dma16(const u16* g, const u16* l) {
    __builtin_amdgcn_global_load_lds(
        (const __attribute__((address_space(1))) u32*)(uintptr_t)g,
        (__attribute__((address_space(3))) u32*)(u32)(uintptr_t)l,
        16, 0, 0);
}

// Fused prep: blocks [0,16384) build Qe+Ke, [16384,24576) build VT,
// block 24576 inits out=fcb.
// Qe is precomputed (R3-verified) so attn's K-loop carries only a 2x bf16x8
// prefetch buffer instead of 8x float4 + 48 f2bf -> kills the R6 VGPR spill.
__global__ __launch_bounds__(256)
void prep_all(const float* __restrict__ Q, const float* __restrict__ K,
              const float* __restrict__ V, const int* __restrict__ eid,
              const float* __restrict__ emb,
              u16* __restrict__ Qe, u16* __restrict__ Ke, u16* __restrict__ VT,
              float* __restrict__ out, const float* __restrict__ fcb)
{
    __shared__ u16 T[64 * 72];
    const int bb = blockIdx.x;
    const int tid = threadIdx.x;

    if (bb < 16384) {
        // ---- Qe/Ke = bf16(Q/K + emb[eid]) row-major [B,N,D] ----
        size_t f = ((size_t)bb * 256 + tid) * 8;
        int n = (int)((f >> 10) & (NN - 1));
        int col = (int)(f & (ND - 1));
        const float* ep = emb + (size_t)eid[n] * ND + col;
        float4 e0 = *(const float4*)ep, e1 = *(const float4*)(ep + 4);
        {
            const float* qp = Q + f;
            float4 x0 = *(const float4*)qp, x1 = *(const float4*)(qp + 4);
            union { uint4 u; u16 s[8]; } o;
            o.s[0]=f2bf(x0.x+e0.x); o.s[1]=f2bf(x0.y+e0.y); o.s[2]=f2bf(x0.z+e0.z); o.s[3]=f2bf(x0.w+e0.w);
            o.s[4]=f2bf(x1.x+e1.x); o.s[5]=f2bf(x1.y+e1.y); o.s[6]=f2bf(x1.z+e1.z); o.s[7]=f2bf(x1.w+e1.w);
            *(uint4*)(Qe + f) = o.u;
        }
        {
            const float* kp = K + f;
            float4 x0 = *(const float4*)kp, x1 = *(const float4*)(kp + 4);
            union { uint4 u; u16 s[8]; } o;
            o.s[0]=f2bf(x0.x+e0.x); o.s[1]=f2bf(x0.y+e0.y); o.s[2]=f2bf(x0.z+e0.z); o.s[3]=f2bf(x0.w+e0.w);
            o.s[4]=f2bf(x1.x+e1.x); o.s[5]=f2bf(x1.y+e1.y); o.s[6]=f2bf(x1.z+e1.z); o.s[7]=f2bf(x1.w+e1.w);
            *(uint4*)(Ke + f) = o.u;
        }
    } else if (bb < 16384 + 8192) {
        // ---- VT[b,d,n] = bf16(V[b,n,d] + emb[eid[n],d]) via 64x64 LDS transpose ----
        // Conflict-free writes: thread = (row-pair r2, 8-col group cg); packs
        // rows {r2, r2+1} of one col as a u32 -> lanes 0-31 span banks
        // (4c + r) mod 32 = all 32 banks; wave halves alias 2-way (free, m136).
        // Old version: scalar ds_write_u16 with 16-way conflicts.
        const int t = bb - 16384;
        const int n0 = (t & 7) * 64, d0 = ((t >> 3) & 15) * 64, b = t >> 7;
        {
            const int r2 = (tid & 31) * 2;   // row pair base
            const int cg = tid >> 5;         // 0..7 -> cols d0+cg*8 .. +8
            const int na = n0 + r2, nb = n0 + r2 + 1;
            const float* vp0 = V + ((size_t)b * NN + na) * ND + d0 + cg * 8;
            const float* vp1 = V + ((size_t)b * NN + nb) * ND + d0 + cg * 8;
            const float* ep0 = emb + (size_t)eid[na] * ND + d0 + cg * 8;
            const float* ep1 = emb + (size_t)eid[nb] * ND + d0 + cg * 8;
            float4 a0 = *(const float4*)vp0,       a1 = *(const float4*)(vp0 + 4);
            float4 b0 = *(const float4*)vp1,       b1 = *(const float4*)(vp1 + 4);
            float4 x0 = *(const float4*)ep0,       x1 = *(const float4*)(ep0 + 4);
            float4 y0 = *(const float4*)ep1,       y1 = *(const float4*)(ep1 + 4);
            float lo[8] = {a0.x+x0.x, a0.y+x0.y, a0.z+x0.z, a0.w+x0.w,
                           a1.x+x1.x, a1.y+x1.y, a1.z+x1.z, a1.w+x1.w};
            float hi[8] = {b0.x+y0.x, b0.y+y0.y, b0.z+y0.z, b0.w+y0.w,
                           b1.x+y1.x, b1.y+y1.y, b1.z+y1.z, b1.w+y1.w};
            #pragma unroll
            for (int j = 0; j < 8; ++j) {
                u32 pk = (u32)f2bf(lo[j]) | ((u32)f2bf(hi[j]) << 16);
                *(u32*)&T[(cg * 8 + j) * 72 + r2] = pk;
            }
        }
        __syncthreads();
        {
            const int dr = tid >> 2, ms = (tid & 3) * 16;
            u16* dst = VT + ((size_t)b * ND + d0 + dr) * NN + n0 + ms;
            *(uint4*)dst       = *(const uint4*)&T[dr * 72 + ms];
            *(uint4*)(dst + 8) = *(const uint4*)&T[dr * 72 + ms + 8];
        }
    } else {
        if (tid < NBATCH * 4) out[tid] = fcb[tid & 3];
    }
}

// One block per (b, 32-row Q tile). Dead-path: neuromod term is per-row const,
// cancels in (ms-mean)/std -> only QK^T -> z-softmax -> PV -> FC survives.
// XCD swizzle: b = (bid&7) + 8*(bid>>7) so all 16 tiles of a batch share an XCD L2.
//
// Barrier-free LDS-DMA pipeline, ORDER-ROBUST (R6-verified): wave w owns KV
// rows [w*128,w*128+128); all waits are vmcnt(0)/lgkmcnt(0) so correctness is
// schedule-independent (counted vmcnt(8) raced in R4/R5). Pipeline cover:
// DMA(KC+1) + Qe(KC+1) loads issue after the KV-read drain and fly across the
// MFMA block. Qe prefetch is 2x bf16x8 (8 regs) -> no spill (R6 spilled 34
// dwords/thread with the 8x float4 + f2bf variant: WRITE_SIZE 34.8MB, 366us).
// FC fused into the epilogue from f32 oacc (no O buffer, no fc_red).
// Plain __launch_bounds__(256): (256,3) caused a 130-reg spill in R2.
__global__ __launch_bounds__(256)
void nma_attn(const u16* __restrict__ Qe, const u16* __restrict__ Ke,
              const u16* __restrict__ VT, const float* __restrict__ fcw,
              float* __restrict__ out)
{
    __shared__ __align__(16) u16 KV[NN * 32];     // 32KB chunk [512 rows][32 cols] bf16
    __shared__ __align__(16) u16 Ps[32 * 520];    // probs bf16
    __shared__ float red[4][32][4];
    __shared__ float rowM[32], rowInv[32], rowRden[32];

    const int tid  = threadIdx.x;
    const int w    = tid >> 6;
    const int lane = tid & 63;
    const int q    = lane >> 4;
    const int l15  = lane & 15;
    const int rr   = lane >> 2;   // DMA: row-within-16
    const int seg  = lane & 3;    // DMA: 16B granule within 64B row
    const int bid  = blockIdx.x;
    const int jj   = bid >> 3;
    const int b    = (bid & 7) + ((jj >> 4) << 3);
    const int i0   = (jj & 15) * 32;
    const size_t bOff = (size_t)b * NN * ND;
    const int wrow = w * 128;     // wave-private KV row base

    const u16* aP0 = Qe + bOff + (size_t)(i0 + l15) * ND + q * 8;
    const u16* aP1 = aP0 + (size_t)16 * ND;
    const u16* KeB = Ke + bOff;
    const u16* VTB = VT + (size_t)b * ND * NN;

#define DMA_KE(KC) do {                                                         \
    _Pragma("unroll")                                                           \
    for (int ii_ = 0; ii_ < 8; ++ii_)                                           \
        dma16(KeB + (size_t)(wrow + ii_ * 16 + rr) * ND + (KC) * 32 + seg * 8,  \
              &KV[(wrow + ii_ * 16) * 32]);                                     \
    } while (0)

#define DMA_VT(H, MC) do {                                                      \
    _Pragma("unroll")                                                           \
    for (int ii_ = 0; ii_ < 8; ++ii_)                                           \
        dma16(VTB + (size_t)((H) * 512 + wrow + ii_ * 16 + rr) * NN             \
                  + (MC) * 32 + seg * 8,                                        \
              &KV[(wrow + ii_ * 16) * 32]);                                     \
    } while (0)

    f32x4 acc[2][8];
    #pragma unroll
    for (int it = 0; it < 2; ++it)
        #pragma unroll
        for (int mt = 0; mt < 8; ++mt)
            acc[it][mt] = (f32x4){0.f, 0.f, 0.f, 0.f};

    // ---- Phase 2: S = Qe * Ke^T (barrier-free, order-robust pipeline) ----
    bf16x8 qc0, qc1, qn0, qn1;
    {   // prologue: chunk-0 Qe loads + chunk-0 DMA; both drained at iter 0's head
        qc0 = *(const bf16x8*)aP0;
        qc1 = *(const bf16x8*)aP1;
        DMA_KE(0);
    }

#define P2BODY(KC, C0, C1, N0, N1) do {                                         \
    asm volatile("s_waitcnt vmcnt(0)" ::: "memory"); /* DMA(KC)+Qe(KC) done */  \
    bf16x8 bfr[8];                                                              \
    _Pragma("unroll")                                                           \
    for (int mt = 0; mt < 8; ++mt)                                              \
        bfr[mt] = *(const bf16x8*)&KV[(wrow + mt * 16 + l15) * 32 + q * 8];     \
    asm volatile("s_waitcnt lgkmcnt(0)" ::: "memory"); /* KV reads in regs */   \
    if ((KC) < 31) {                                                            \
        DMA_KE((KC) + 1);                 /* overwrite safe: reads drained */   \
        N0 = *(const bf16x8*)(aP0 + ((KC) + 1) * 32);  /* flies across MFMA */  \
        N1 = *(const bf16x8*)(aP1 + ((KC) + 1) * 32);                           \
    }                                                                           \
    _Pragma("unroll")                                                           \
    for (int mt = 0; mt < 8; ++mt) {                                            \
        acc[0][mt] = __builtin_amdgcn_mfma_f32_16x16x32_bf16(C0, bfr[mt], acc[0][mt], 0, 0, 0); \
        acc[1][mt] = __builtin_amdgcn_mfma_f32_16x16x32_bf16(C1, bfr[mt], acc[1][mt], 0, 0, 0); \
    } } while (0)

    for (int kc = 0; kc < 32; kc += 2) {
        P2BODY(kc,     qc0, qc1, qn0, qn1);
        P2BODY(kc + 1, qn0, qn1, qc0, qc1);
    }

    // ---- Phase 3: exact row stats (mean, ddof=1 std, max), softmax(z) ----
    const float SC = 0.03125f;
    #pragma unroll
    for (int it = 0; it < 2; ++it)
        #pragma unroll
        for (int mt = 0; mt < 8; ++mt) {
            acc[it][mt][0] *= SC; acc[it][mt][1] *= SC;
            acc[it][mt][2] *= SC; acc[it][mt][3] *= SC;
        }
    float ssum[2][4], ssq[2][4], smax[2][4];
    #pragma unroll
    for (int it = 0; it < 2; ++it)
        #pragma unroll
        for (int r = 0; r < 4; ++r) {
            float s = 0.f, s2 = 0.f, mx = -3.4e38f;
            #pragma unroll
            for (int mt = 0; mt < 8; ++mt) {
                float v = acc[it][mt][r];
                s += v; s2 += v * v; mx = fmaxf(mx, v);
            }
            #pragma unroll
            for (int d = 1; d < 16; d <<= 1) {
                s  += __shfl_xor(s, d);
                s2 += __shfl_xor(s2, d);
                mx  = fmaxf(mx, __shfl_xor(mx, d));
            }
            ssum[it][r] = s; ssq[it][r] = s2; smax[it][r] = mx;
        }
    if (l15 == 0) {
        #pragma unroll
        for (int it = 0; it < 2; ++it)
            #pragma unroll
            for (int r = 0; r < 4; ++r) {
                int i = it * 16 + q * 4 + r;
                red[w][i][0] = ssum[it][r];
                red[w][i][1] = ssq[it][r];
                red[w][i][2] = smax[it][r];
            }
    }
    __syncthreads();
    if (tid < 32) {
        float s  = red[0][tid][0] + red[1][tid][0] + red[2][tid][0] + red[3][tid][0];
        float s2 = red[0][tid][1] + red[1][tid][1] + red[2][tid][1] + red[3][tid][1];
        float mx = fmaxf(fmaxf(red[0][tid][2], red[1][tid][2]),
                         fmaxf(red[2][tid][2], red[3][tid][2]));
        float mu  = s * (1.f / 512.f);
        float var = fmaxf((s2 - s * mu) * (1.f / 511.f), 0.f);
        float sd  = sqrtf(var);
        rowM[tid]   = mx;
        rowInv[tid] = 1.f / (sd + 1e-6f);
    }
    __syncthreads();
    float dsum[2][4];
    #pragma unroll
    for (int it = 0; it < 2; ++it)
        #pragma unroll
        for (int r = 0; r < 4; ++r) {
            int i = it * 16 + q * 4 + r;
            float M = rowM[i], inv = rowInv[i];
            float s = 0.f;
            #pragma unroll
            for (int mt = 0; mt < 8; ++mt) {
                float e = __expf((acc[it][mt][r] - M) * inv);
                acc[it][mt][r] = e; s += e;
            }
            #pragma unroll
            for (int d = 1; d < 16; d <<= 1) s += __shfl_xor(s, d);
            dsum[it][r] = s;
        }
    if (l15 == 0) {
        #pragma unroll
        for (int it = 0; it < 2; ++it)
            #pragma unroll
            for (int r = 0; r < 4; ++r)
                red[w][it * 16 + q * 4 + r][0] = dsum[it][r];
    }
    __syncthreads();
    if (tid < 32)
        rowRden[tid] = 1.f / (red[0][tid][0] + red[1][tid][0] + red[2][tid][0] + red[3][tid][0]);
    __syncthreads();
    #pragma unroll
    for (int it = 0; it < 2; ++it)
        #pragma unroll
        for (int r = 0; r < 4; ++r) {
            int i = it * 16 + q * 4 + r;
            float rd = rowRden[i];
            #pragma unroll
            for (int mt = 0; mt < 8; ++mt) {
                int m = w * 128 + mt * 16 + l15;
                Ps[i * 520 + m] = f2bf(acc[it][mt][r] * rd);
            }
        }
    __syncthreads();   // Ps produced by all waves -> consumed by all waves

    // ---- Phase 4: O = P * Ve (barrier-free, all-vmcnt(0)) + fused FC ----
    DMA_VT(0, 0);      // right after the barrier; drained by first vmcnt(0)
    float fsum[4] = {0.f, 0.f, 0.f, 0.f};
    for (int h = 0; h < 2; ++h) {
        f32x4 oacc[2][8];
        #pragma unroll
        for (int it = 0; it < 2; ++it)
            #pragma unroll
            for (int dt = 0; dt < 8; ++dt)
                oacc[it][dt] = (f32x4){0.f, 0.f, 0.f, 0.f};
        for (int mc = 0; mc < 16; ++mc) {
            // P reads are DMA-independent: issue them before the vmcnt stall
            bf16x8 p0 = *(const bf16x8*)&Ps[l15 * 520 + mc * 32 + q * 8];
            bf16x8 p1 = *(const bf16x8*)&Ps[(16 + l15) * 520 + mc * 32 + q * 8];
            asm volatile("s_waitcnt vmcnt(0)" ::: "memory");  // chunk ready
            bf16x8 bfr[8];
            #pragma unroll
            for (int dt = 0; dt < 8; ++dt)
                bfr[dt] = *(const bf16x8*)&KV[(wrow + dt * 16 + l15) * 32 + q * 8];
            asm volatile("s_waitcnt lgkmcnt(0)" ::: "memory");
            const int j = h * 16 + mc;
            if (j < 31) {
                const int jn = j + 1;
                DMA_VT(jn >> 4, jn & 15);   // overlap next chunk with MFMA
            }
            #pragma unroll
            for (int dt = 0; dt < 8; ++dt) {
                oacc[0][dt] = __builtin_amdgcn_mfma_f32_16x16x32_bf16(p0, bfr[dt], oacc[0][dt], 0, 0, 0);
                oacc[1][dt] = __builtin_amdgcn_mfma_f32_16x16x32_bf16(p1, bfr[dt], oacc[1][dt], 0, 0, 0);
            }
        }
        // fused FC: out[b,c] += sum oacc[it][dt][r] * fcw[c, iglob*D + dglob]
        #pragma unroll
        for (int it = 0; it < 2; ++it) {
            #pragma unroll
            for (int r = 0; r < 4; ++r) {
                const int iglob = i0 + it * 16 + q * 4 + r;
                const float* fr = fcw + (size_t)iglob * ND + (h * 512 + wrow + l15);
                #pragma unroll
                for (int dt = 0; dt < 8; ++dt) {
                    const float o = oacc[it][dt][r];
                    fsum[0] += o * fr[dt * 16];
                    fsum[1] += o * fr[(size_t)NDW + dt * 16];
                    fsum[2] += o * fr[(size_t)2 * NDW + dt * 16];
                    fsum[3] += o * fr[(size_t)3 * NDW + dt * 16];
                }
            }
        }
    }
    // block-reduce fsum -> 4 atomics (red[] is free after the Ps barrier)
    #pragma unroll
    for (int c = 0; c < 4; ++c)
        #pragma unroll
        for (int d = 1; d < 64; d <<= 1)
            fsum[c] += __shfl_xor(fsum[c], d);
    if (lane == 0) {
        red[w][0][0] = fsum[0]; red[w][0][1] = fsum[1];
        red[w][0][2] = fsum[2]; red[w][0][3] = fsum[3];
    }
    __syncthreads();
    if (tid < 4) {
        float s = red[0][0][tid] + red[1][0][tid] + red[2][0][tid] + red[3][0][tid];
        atomicAdd(&out[b * 4 + tid], s);
    }
#undef P2BODY
#undef DMA_KE
#undef DMA_VT
}

extern "C" void kernel_launch(void* const* d_in, const int* in_sizes, int n_in,
                              void* d_out, int out_size, void* d_ws, size_t ws_size,
                              hipStream_t stream) {
    (void)in_sizes; (void)n_in; (void)ws_size; (void)out_size;
    const float* Q   = (const float*)d_in[0];
    const float* K   = (const float*)d_in[1];
    const float* V   = (const float*)d_in[2];
    const int*   eid = (const int*)d_in[3];
    const float* emb = (const float*)d_in[4];
    const float* fcw = (const float*)d_in[15];
    const float* fcb = (const float*)d_in[16];
    float* out = (float*)d_out;

    u16* Qe = (u16*)d_ws;
    u16* Ke = Qe + (size_t)NBATCH * NN * ND;   // +64MB
    u16* VT = Ke + (size_t)NBATCH * NN * ND;   // +64MB (total ws use: 192MB)

    prep_all<<<dim3(16384 + 8192 + 1), dim3(256), 0, stream>>>(
        Q, K, V, eid, emb, Qe, Ke, VT, out, fcb);
    nma_attn<<<dim3(1024), dim3(256), 0, stream>>>(Qe, Ke, VT, fcw, out);
}

// Round 8
// 655.253 us; speedup vs baseline: 1.2230x; 1.0400x over previous
//
#include <hip/hip_runtime.h>

#define NN 512
#define ND 1024
#define NDW 524288   // N*D
#define NBATCH 64

typedef __attribute__((ext_vector_type(8))) __bf16 bf16x8;
typedef __attribute__((ext_vector_type(4))) float f32x4;
typedef unsigned short u16;
typedef unsigned int u32;

__device__ __forceinline__ u16 f2bf(float x) {
    u32 u = __float_as_uint(x);
    u = (u + 0x7fffu + ((u >> 16) & 1u)) >> 16;   // RNE
    return (u16)u;
}

// async global->LDS DMA, 16B per lane; LDS dest = wave-uniform base + lane*16
__device__ __forceinline__ void dma16(const u16* g, const u16* l) {
    __builtin_amdgcn_global_load_lds(
        (const __attribute__((address_space(1))) u32*)(uintptr_t)g,
        (__attribute__((address_space(3))) u32*)(u32)(uintptr_t)l,
        16, 0, 0);
}

// Fused prep: blocks [0,16384) build Qe+Ke, [16384,24576) build VT,
// block 24576 inits out=fcb. (R7-verified, unchanged.)
__global__ __launch_bounds__(256)
void prep_all(const float* __restrict__ Q, const float* __restrict__ K,
              const float* __restrict__ V, const int* __restrict__ eid,
              const float* __restrict__ emb,
              u16* __restrict__ Qe, u16* __restrict__ Ke, u16* __restrict__ VT,
              float* __restrict__ out, const float* __restrict__ fcb)
{
    __shared__ u16 T[64 * 72];
    const int bb = blockIdx.x;
    const int tid = threadIdx.x;

    if (bb < 16384) {
        // ---- Qe/Ke = bf16(Q/K + emb[eid]) row-major [B,N,D] ----
        size_t f = ((size_t)bb * 256 + tid) * 8;
        int n = (int)((f >> 10) & (NN - 1));
        int col = (int)(f & (ND - 1));
        const float* ep = emb + (size_t)eid[n] * ND + col;
        float4 e0 = *(const float4*)ep, e1 = *(const float4*)(ep + 4);
        {
            const float* qp = Q + f;
            float4 x0 = *(const float4*)qp, x1 = *(const float4*)(qp + 4);
            union { uint4 u; u16 s[8]; } o;
            o.s[0]=f2bf(x0.x+e0.x); o.s[1]=f2bf(x0.y+e0.y); o.s[2]=f2bf(x0.z+e0.z); o.s[3]=f2bf(x0.w+e0.w);
            o.s[4]=f2bf(x1.x+e1.x); o.s[5]=f2bf(x1.y+e1.y); o.s[6]=f2bf(x1.z+e1.z); o.s[7]=f2bf(x1.w+e1.w);
            *(uint4*)(Qe + f) = o.u;
        }
        {
            const float* kp = K + f;
            float4 x0 = *(const float4*)kp, x1 = *(const float4*)(kp + 4);
            union { uint4 u; u16 s[8]; } o;
            o.s[0]=f2bf(x0.x+e0.x); o.s[1]=f2bf(x0.y+e0.y); o.s[2]=f2bf(x0.z+e0.z); o.s[3]=f2bf(x0.w+e0.w);
            o.s[4]=f2bf(x1.x+e1.x); o.s[5]=f2bf(x1.y+e1.y); o.s[6]=f2bf(x1.z+e1.z); o.s[7]=f2bf(x1.w+e1.w);
            *(uint4*)(Ke + f) = o.u;
        }
    } else if (bb < 16384 + 8192) {
        // ---- VT[b,d,n] = bf16(V[b,n,d] + emb[eid[n],d]) via 64x64 LDS transpose ----
        // Conflict-free packed-u32 writes (R7-verified).
        const int t = bb - 16384;
        const int n0 = (t & 7) * 64, d0 = ((t >> 3) & 15) * 64, b = t >> 7;
        {
            const int r2 = (tid & 31) * 2;   // row pair base
            const int cg = tid >> 5;         // 0..7 -> cols d0+cg*8 .. +8
            const int na = n0 + r2, nb = n0 + r2 + 1;
            const float* vp0 = V + ((size_t)b * NN + na) * ND + d0 + cg * 8;
            const float* vp1 = V + ((size_t)b * NN + nb) * ND + d0 + cg * 8;
            const float* ep0 = emb + (size_t)eid[na] * ND + d0 + cg * 8;
            const float* ep1 = emb + (size_t)eid[nb] * ND + d0 + cg * 8;
            float4 a0 = *(const float4*)vp0,       a1 = *(const float4*)(vp0 + 4);
            float4 b0 = *(const float4*)vp1,       b1 = *(const float4*)(vp1 + 4);
            float4 x0 = *(const float4*)ep0,       x1 = *(const float4*)(ep0 + 4);
            float4 y0 = *(const float4*)ep1,       y1 = *(const float4*)(ep1 + 4);
            float lo[8] = {a0.x+x0.x, a0.y+x0.y, a0.z+x0.z, a0.w+x0.w,
                           a1.x+x1.x, a1.y+x1.y, a1.z+x1.z, a1.w+x1.w};
            float hi[8] = {b0.x+y0.x, b0.y+y0.y, b0.z+y0.z, b0.w+y0.w,
                           b1.x+y1.x, b1.y+y1.y, b1.z+y1.z, b1.w+y1.w};
            #pragma unroll
            for (int j = 0; j < 8; ++j) {
                u32 pk = (u32)f2bf(lo[j]) | ((u32)f2bf(hi[j]) << 16);
                *(u32*)&T[(cg * 8 + j) * 72 + r2] = pk;
            }
        }
        __syncthreads();
        {
            const int dr = tid >> 2, ms = (tid & 3) * 16;
            u16* dst = VT + ((size_t)b * ND + d0 + dr) * NN + n0 + ms;
            *(uint4*)dst       = *(const uint4*)&T[dr * 72 + ms];
            *(uint4*)(dst + 8) = *(const uint4*)&T[dr * 72 + ms + 8];
        }
    } else {
        if (tid < NBATCH * 4) out[tid] = fcb[tid & 3];
    }
}

// One block per (b, 32-row Q tile), 512 threads = 8 waves. Wave w owns KV rows
// [w*64, w*64+64): per-wave register state halves vs the 4-wave version
// (acc 32, oacc 32, bfr 16 -> ~100 live regs), fitting launch_bounds(512,4)'s
// 128-reg cap -> 4 waves/SIMD, 2 blocks/CU (R7 was stuck at 256 regs + 34.8MB
// scratch spill + 2 waves/SIMD). Same order-robust vmcnt(0)/lgkmcnt(0) pipeline
// (R6/R7-verified); all sync structure unchanged, only ownership re-parameterized.
// NOTE: SQ_LDS_BANK_CONFLICT ~9.4M is the DMA LDS-write-port floor (identical
// across R0/R1/R6/R7; KV b128 reads are bank-balanced) — not actionable.
// FC fused into the epilogue from f32 oacc (no O buffer, no fc_red).
__global__ __launch_bounds__(512, 4)
void nma_attn(const u16* __restrict__ Qe, const u16* __restrict__ Ke,
              const u16* __restrict__ VT, const float* __restrict__ fcw,
              float* __restrict__ out)
{
    __shared__ __align__(16) u16 KV[NN * 32];     // 32KB chunk [512 rows][32 cols] bf16
    __shared__ __align__(16) u16 Ps[32 * 520];    // probs bf16
    __shared__ float red[8][32][4];
    __shared__ float rowM[32], rowInv[32], rowRden[32];

    const int tid  = threadIdx.x;
    const int w    = tid >> 6;
    const int lane = tid & 63;
    const int q    = lane >> 4;
    const int l15  = lane & 15;
    const int rr   = lane >> 2;   // DMA: row-within-16
    const int seg  = lane & 3;    // DMA: 16B granule within 64B row
    const int bid  = blockIdx.x;
    const int jj   = bid >> 3;
    const int b    = (bid & 7) + ((jj >> 4) << 3);
    const int i0   = (jj & 15) * 32;
    const size_t bOff = (size_t)b * NN * ND;
    const int wrow = w * 64;      // wave-private KV row base (64 rows/wave)

    const u16* aP0 = Qe + bOff + (size_t)(i0 + l15) * ND + q * 8;
    const u16* aP1 = aP0 + (size_t)16 * ND;
    const u16* KeB = Ke + bOff;
    const u16* VTB = VT + (size_t)b * ND * NN;

#define DMA_KE(KC) do {                                                         \
    _Pragma("unroll")                                                           \
    for (int ii_ = 0; ii_ < 4; ++ii_)                                           \
        dma16(KeB + (size_t)(wrow + ii_ * 16 + rr) * ND + (KC) * 32 + seg * 8,  \
              &KV[(wrow + ii_ * 16) * 32]);                                     \
    } while (0)

#define DMA_VT(H, MC) do {                                                      \
    _Pragma("unroll")                                                           \
    for (int ii_ = 0; ii_ < 4; ++ii_)                                           \
        dma16(VTB + (size_t)((H) * 512 + wrow + ii_ * 16 + rr) * NN             \
                  + (MC) * 32 + seg * 8,                                        \
              &KV[(wrow + ii_ * 16) * 32]);                                     \
    } while (0)

    f32x4 acc[2][4];
    #pragma unroll
    for (int it = 0; it < 2; ++it)
        #pragma unroll
        for (int mt = 0; mt < 4; ++mt)
            acc[it][mt] = (f32x4){0.f, 0.f, 0.f, 0.f};

    // ---- Phase 2: S = Qe * Ke^T (barrier-free, order-robust pipeline) ----
    bf16x8 qc0, qc1, qn0, qn1;
    {   // prologue: chunk-0 Qe loads + chunk-0 DMA; both drained at iter 0's head
        qc0 = *(const bf16x8*)aP0;
        qc1 = *(const bf16x8*)aP1;
        DMA_KE(0);
    }

#define P2BODY(KC, C0, C1, N0, N1) do {                                         \
    asm volatile("s_waitcnt vmcnt(0)" ::: "memory"); /* DMA(KC)+Qe(KC) done */  \
    bf16x8 bfr[4];                                                              \
    _Pragma("unroll")                                                           \
    for (int mt = 0; mt < 4; ++mt)                                              \
        bfr[mt] = *(const bf16x8*)&KV[(wrow + mt * 16 + l15) * 32 + q * 8];     \
    asm volatile("s_waitcnt lgkmcnt(0)" ::: "memory"); /* KV reads in regs */   \
    if ((KC) < 31) {                                                            \
        DMA_KE((KC) + 1);                 /* overwrite safe: reads drained */   \
        N0 = *(const bf16x8*)(aP0 + ((KC) + 1) * 32);  /* flies across MFMA */  \
        N1 = *(const bf16x8*)(aP1 + ((KC) + 1) * 32);                           \
    }                                                                           \
    _Pragma("unroll")                                                           \
    for (int mt = 0; mt < 4; ++mt) {                                            \
        acc[0][mt] = __builtin_amdgcn_mfma_f32_16x16x32_bf16(C0, bfr[mt], acc[0][mt], 0, 0, 0); \
        acc[1][mt] = __builtin_amdgcn_mfma_f32_16x16x32_bf16(C1, bfr[mt], acc[1][mt], 0, 0, 0); \
    } } while (0)

    for (int kc = 0; kc < 32; kc += 2) {
        P2BODY(kc,     qc0, qc1, qn0, qn1);
        P2BODY(kc + 1, qn0, qn1, qc0, qc1);
    }

    // ---- Phase 3: exact row stats (mean, ddof=1 std, max), softmax(z) ----
    const float SC = 0.03125f;
    #pragma unroll
    for (int it = 0; it < 2; ++it)
        #pragma unroll
        for (int mt = 0; mt < 4; ++mt) {
            acc[it][mt][0] *= SC; acc[it][mt][1] *= SC;
            acc[it][mt][2] *= SC; acc[it][mt][3] *= SC;
        }
    float ssum[2][4], ssq[2][4], smax[2][4];
    #pragma unroll
    for (int it = 0; it < 2; ++it)
        #pragma unroll
        for (int r = 0; r < 4; ++r) {
            float s = 0.f, s2 = 0.f, mx = -3.4e38f;
            #pragma unroll
            for (int mt = 0; mt < 4; ++mt) {
                float v = acc[it][mt][r];
                s += v; s2 += v * v; mx = fmaxf(mx, v);
            }
            #pragma unroll
            for (int d = 1; d < 16; d <<= 1) {
                s  += __shfl_xor(s, d);
                s2 += __shfl_xor(s2, d);
                mx  = fmaxf(mx, __shfl_xor(mx, d));
            }
            ssum[it][r] = s; ssq[it][r] = s2; smax[it][r] = mx;
        }
    if (l15 == 0) {
        #pragma unroll
        for (int it = 0; it < 2; ++it)
            #pragma unroll
            for (int r = 0; r < 4; ++r) {
                int i = it * 16 + q * 4 + r;
                red[w][i][0] = ssum[it][r];
                red[w][i][1] = ssq[it][r];
                red[w][i][2] = smax[it][r];
            }
    }
    __syncthreads();
    if (tid < 32) {
        float s = 0.f, s2 = 0.f, mx = -3.4e38f;
        #pragma unroll
        for (int ww = 0; ww < 8; ++ww) {
            s  += red[ww][tid][0];
            s2 += red[ww][tid][1];
            mx  = fmaxf(mx, red[ww][tid][2]);
        }
        float mu  = s * (1.f / 512.f);
        float var = fmaxf((s2 - s * mu) * (1.f / 511.f), 0.f);
        float sd  = sqrtf(var);
        rowM[tid]   = mx;
        rowInv[tid] = 1.f / (sd + 1e-6f);
    }
    __syncthreads();
    float dsum[2][4];
    #pragma unroll
    for (int it = 0; it < 2; ++it)
        #pragma unroll
        for (int r = 0; r < 4; ++r) {
            int i = it * 16 + q * 4 + r;
            float M = rowM[i], inv = rowInv[i];
            float s = 0.f;
            #pragma unroll
            for (int mt = 0; mt < 4; ++mt) {
                float e = __expf((acc[it][mt][r] - M) * inv);
                acc[it][mt][r] = e; s += e;
            }
            #pragma unroll
            for (int d = 1; d < 16; d <<= 1) s += __shfl_xor(s, d);
            dsum[it][r] = s;
        }
    if (l15 == 0) {
        #pragma unroll
        for (int it = 0; it < 2; ++it)
            #pragma unroll
            for (int r = 0; r < 4; ++r)
                red[w][it * 16 + q * 4 + r][0] = dsum[it][r];
    }
    __syncthreads();
    if (tid < 32) {
        float s = 0.f;
        #pragma unroll
        for (int ww = 0; ww < 8; ++ww) s += red[ww][tid][0];
        rowRden[tid] = 1.f / s;
    }
    __syncthreads();
    #pragma unroll
    for (int it = 0; it < 2; ++it)
        #pragma unroll
        for (int r = 0; r < 4; ++r) {
            int i = it * 16 + q * 4 + r;
            float rd = rowRden[i];
            #pragma unroll
            for (int mt = 0; mt < 4; ++mt) {
                int m = wrow + mt * 16 + l15;
                Ps[i * 520 + m] = f2bf(acc[it][mt][r] * rd);
            }
        }
    __syncthreads();   // Ps produced by all waves -> consumed by all waves

    // ---- Phase 4: O = P * Ve (barrier-free, all-vmcnt(0)) + fused FC ----
    DMA_VT(0, 0);      // right after the barrier (R1/R6 placement)
    float fsum[4] = {0.f, 0.f, 0.f, 0.f};
    for (int h = 0; h < 2; ++h) {
        f32x4 oacc[2][4];
        #pragma unroll
        for (int it = 0; it < 2; ++it)
            #pragma unroll
            for (int dt = 0; dt < 4; ++dt)
                oacc[it][dt] = (f32x4){0.f, 0.f, 0.f, 0.f};
        for (int mc = 0; mc < 16; ++mc) {
            // P reads are DMA-independent: issue them before the vmcnt stall
            bf16x8 p0 = *(const bf16x8*)&Ps[l15 * 520 + mc * 32 + q * 8];
            bf16x8 p1 = *(const bf16x8*)&Ps[(16 + l15) * 520 + mc * 32 + q * 8];
            asm volatile("s_waitcnt vmcnt(0)" ::: "memory");  // chunk ready
            bf16x8 bfr[4];
            #pragma unroll
            for (int dt = 0; dt < 4; ++dt)
                bfr[dt] = *(const bf16x8*)&KV[(wrow + dt * 16 + l15) * 32 + q * 8];
            asm volatile("s_waitcnt lgkmcnt(0)" ::: "memory");
            const int j = h * 16 + mc;
            if (j < 31) {
                const int jn = j + 1;
                DMA_VT(jn >> 4, jn & 15);   // overlap next chunk with MFMA
            }
            #pragma unroll
            for (int dt = 0; dt < 4; ++dt) {
                oacc[0][dt] = __builtin_amdgcn_mfma_f32_16x16x32_bf16(p0, bfr[dt], oacc[0][dt], 0, 0, 0);
                oacc[1][dt] = __builtin_amdgcn_mfma_f32_16x16x32_bf16(p1, bfr[dt], oacc[1][dt], 0, 0, 0);
            }
        }
        // fused FC: out[b,c] += sum oacc[it][dt][r] * fcw[c, iglob*D + dglob]
        #pragma unroll
        for (int it = 0; it < 2; ++it) {
            #pragma unroll
            for (int r = 0; r < 4; ++r) {
                const int iglob = i0 + it * 16 + q * 4 + r;
                const float* fr = fcw + (size_t)iglob * ND + (h * 512 + wrow + l15);
                #pragma unroll
                for (int dt = 0; dt < 4; ++dt) {
                    const float o = oacc[it][dt][r];
                    fsum[0] += o * fr[dt * 16];
                    fsum[1] += o * fr[(size_t)NDW + dt * 16];
                    fsum[2] += o * fr[(size_t)2 * NDW + dt * 16];
                    fsum[3] += o * fr[(size_t)3 * NDW + dt * 16];
                }
            }
        }
    }
    // block-reduce fsum -> 4 atomics (red[] is free after the Ps barrier)
    #pragma unroll
    for (int c = 0; c < 4; ++c)
        #pragma unroll
        for (int d = 1; d < 64; d <<= 1)
            fsum[c] += __shfl_xor(fsum[c], d);
    if (lane == 0) {
        red[w][0][0] = fsum[0]; red[w][0][1] = fsum[1];
        red[w][0][2] = fsum[2]; red[w][0][3] = fsum[3];
    }
    __syncthreads();
    if (tid < 4) {
        float s = 0.f;
        #pragma unroll
        for (int ww = 0; ww < 8; ++ww) s += red[ww][0][tid];
        atomicAdd(&out[b * 4 + tid], s);
    }
#undef P2BODY
#undef DMA_KE
#undef DMA_VT
}

extern "C" void kernel_launch(void* const* d_in, const int* in_sizes, int n_in,
                              void* d_out, int out_size, void* d_ws, size_t ws_size,
                              hipStream_t stream) {
    (void)in_sizes; (void)n_in; (void)ws_size; (void)out_size;
    const float* Q   = (const float*)d_in[0];
    const float* K   = (const float*)d_in[1];
    const float* V   = (const float*)d_in[2];
    const int*   eid = (const int*)d_in[3];
    const float* emb = (const float*)d_in[4];
    const float* fcw = (const float*)d_in[15];
    const float* fcb = (const float*)d_in[16];
    float* out = (float*)d_out;

    u16* Qe = (u16*)d_ws;
    u16* Ke = Qe + (size_t)NBATCH * NN * ND;   // +64MB
    u16* VT = Ke + (size_t)NBATCH * NN * ND;   // +64MB (total ws use: 192MB)

    prep_all<<<dim3(16384 + 8192 + 1), dim3(256), 0, stream>>>(
        Q, K, V, eid, emb, Qe, Ke, VT, out, fcb);
    nma_attn<<<dim3(1024), dim3(512), 0, stream>>>(Qe, Ke, VT, fcw, out);
}